// Round 3
// baseline (244.008 us; speedup 1.0000x reference)
//
#include <hip/hip_runtime.h>
#include <hip/hip_cooperative_groups.h>

// x: [B=2, C=16, D1=8, D2=8, D3=64, D4=64] fp32
// w: [O=32, I=16, 3,3,3,3] fp32
// out = relu(conv4d_valid(x, w)): [2, 32, 6, 6, 62, 62] fp32
//
// Per tap: D[32 e4-pix][32 o] += A[pix][16 c] * B[16 c][32 o]
// (v_mfma_f32_32x32x16_bf16, fp32 acc, 81 taps).
// Block = (b,e1,e2, 6 e3 rows, 64 e4), 256 threads = 4 waves (the R1
// structure that measured 111.0; the 2-wave R2 variant regressed to 114.8
// -> occupancy/latency-hiding dominates the LDS-read-pipe model).
// This round: ONE cooperative kernel replaces [prep; conv] to remove the
// inter-dispatch drain+ramp. grid=768 = exactly 3 blocks/CU (LDS 51.7KB,
// launch_bounds(256,3)); prep grid-strided over 2080 vblocks, grid.sync(),
// conv grid-strided over 792 units. Fallback to the two-kernel path if
// cooperative launch is rejected by graph capture.

typedef __attribute__((ext_vector_type(8))) __bf16 bf16x8;
typedef __attribute__((ext_vector_type(16))) float f32x16;

#define CSTRIDE 262144  // x channel stride, elements

#define WT_OFF 0       // wT[t81][o32][c16] bf16 = 83 KB
#define XB_OFF 131072  // xb[b][d1][d2][d3][ch2][col64][c8] bf16 = 16.78 MB
#define BOFF 16640     // B region inside a buffer (after 16 KB A + 256 pad)
#define BUF 25856      // per-buffer: A 16.25 KB + B 9 KB

typedef __attribute__((address_space(1))) const unsigned int gu32;
typedef __attribute__((address_space(3))) unsigned int lu32;

__device__ __forceinline__ void async_cp16(const void* g, void* l) {
  __builtin_amdgcn_global_load_lds((gu32*)g, (lu32*)l, 16, 0, 0);
}

// ---- prep unit: vb < 2048 transforms x -> xb; vb 2048..2079 builds wT
__device__ __forceinline__ void prep_unit(int vb, const float* __restrict__ x,
                                          const float* __restrict__ w,
                                          unsigned char* __restrict__ ws) {
  if (vb < 2048) {
    __bf16* xb = (__bf16*)(ws + XB_OFF);
    int n = vb * 256 + threadIdx.x;  // (b,d1,d2,d3,col)
    int col = n & 63;
    int d3 = (n >> 6) & 63;
    int d2 = (n >> 12) & 7;
    int d1 = (n >> 15) & 7;
    int b = n >> 18;
    const float* gx =
        x + ((((size_t)(b * 16) * 8 + d1) * 8 + d2) * 64 + d3) * 64 + col;
    float v[16];
#pragma unroll
    for (int c = 0; c < 16; ++c) v[c] = gx[(size_t)c * CSTRIDE];
    __bf16* row = xb + ((((b * 8 + d1) * 8 + d2) * 64 + d3) * 1024);
#pragma unroll
    for (int ch = 0; ch < 2; ++ch) {
      bf16x8 o;
#pragma unroll
      for (int cc = 0; cc < 8; ++cc) o[cc] = (__bf16)v[ch * 8 + cc];
      *(bf16x8*)(row + ch * 512 + col * 8) = o;
    }
  } else {
    int o = vb - 2048;
    __bf16* wT = (__bf16*)(ws + WT_OFF);
#pragma unroll
    for (int base = 0; base < 1296; base += 256) {
      int idx = base + threadIdx.x;
      if (idx < 1296) {
        int c = idx / 81, t = idx % 81;
        wT[t * 512 + o * 16 + c] = (__bf16)w[o * 1296 + idx];
      }
    }
  }
}

__global__ __launch_bounds__(256) void prep(const float* __restrict__ x,
                                            const float* __restrict__ w,
                                            unsigned char* __restrict__ ws) {
  prep_unit(blockIdx.x, x, w, ws);
}

// NT = tiles per wave (3 normal chunks, 1 for the 2-row tail chunk)
template <int NT>
__device__ __forceinline__ void conv_body(
    const unsigned char* __restrict__ wTb, const unsigned char* __restrict__ xbb,
    float* __restrict__ out, unsigned char* lds, int b, int e1, int e2,
    int r0) {
  int lane = threadIdx.x & 63;
  int wave = threadIdx.x >> 6;
  int m32 = lane & 31;
  int half = lane >> 5;
  int rg = wave >> 1;  // row-group
  int th = wave & 1;   // e4 half
  int rowbase = rg * NT;
  const int nckA = (NT * 2 + 2) * 2;  // staged A 1KB chunks: (rows+2 halo)*2
  const int nck = nckA + 9;           // + 9 B chunks

  int ab_off = half * 1024 + (th * 32 + m32) * 16;
  int bb_off = m32 * 32 + half * 16;

  f32x16 acc[NT];
#pragma unroll
  for (int i = 0; i < NT; ++i)
#pragma unroll
    for (int r = 0; r < 16; ++r) acc[i][r] = 0.f;

  // prologue: stage phase 0 (A tile + wT slice) into buf 0
  {
    const unsigned char* gA =
        xbb + (size_t)(((b * 8 + e1) * 8 + e2) * 64 + r0) * 2048;
#pragma unroll
    for (int j = 0; j < 7; ++j) {
      int ck = j * 4 + wave;
      if (ck < nckA)
        async_cp16(gA + ck * 1024 + lane * 16, lds + ck * 1024);
      else if (ck < nck)
        async_cp16(wTb + (ck - nckA) * 1024 + lane * 16,
                   lds + BOFF + (ck - nckA) * 1024);
    }
  }

  for (int p = 0; p < 9; ++p) {  // phase = (k1,k2)
    __syncthreads();  // stage(p) visible; buf[(p+1)&1] free
    if (p < 8) {
      int np = p + 1;
      int nk1 = np / 3, nk2 = np - nk1 * 3;
      const unsigned char* gA =
          xbb + (size_t)(((b * 8 + e1 + nk1) * 8 + e2 + nk2) * 64 + r0) * 2048;
      const unsigned char* gB = wTb + np * 9216;
      unsigned char* dst = lds + (np & 1) * BUF;
#pragma unroll
      for (int j = 0; j < 7; ++j) {
        int ck = j * 4 + wave;
        if (ck < nckA)
          async_cp16(gA + ck * 1024 + lane * 16, dst + ck * 1024);
        else if (ck < nck)
          async_cp16(gB + (ck - nckA) * 1024 + lane * 16,
                     dst + BOFF + (ck - nckA) * 1024);
      }
    }
    // compute: A and B from LDS; 5 row-frags serve 9 MFMAs per k4
    const unsigned char* bufp = lds + (p & 1) * BUF;
    bf16x8 bfr[9];
#pragma unroll
    for (int t9 = 0; t9 < 9; ++t9)
      bfr[t9] = *(const bf16x8*)(bufp + BOFF + t9 * 1024 + bb_off);
    const unsigned char* abase = bufp + rowbase * 2048 + ab_off;
    __builtin_amdgcn_s_setprio(1);
#pragma unroll
    for (int k4 = 0; k4 < 3; ++k4) {
      bf16x8 arow[NT + 2];
#pragma unroll
      for (int j = 0; j < NT + 2; ++j)
        arow[j] = *(const bf16x8*)(abase + j * 2048 + k4 * 16);
#pragma unroll
      for (int k3 = 0; k3 < 3; ++k3) {
        bf16x8 bf = bfr[k3 * 3 + k4];
#pragma unroll
        for (int i = 0; i < NT; ++i)
          acc[i] = __builtin_amdgcn_mfma_f32_32x32x16_bf16(arow[i + k3], bf,
                                                           acc[i], 0, 0, 0);
      }
    }
    __builtin_amdgcn_s_setprio(0);
  }
  __syncthreads();  // all ds_reads done before scratch overwrite

  // epilogue: per-wave LDS transpose (stride 33) in buf0 space, ReLU, store
  float* sc = (float*)(void*)lds + wave * 1056;
  int e4 = th * 32 + m32;
#pragma unroll
  for (int i = 0; i < NT; ++i) {
    int e3 = r0 + rowbase + i;
#pragma unroll
    for (int r = 0; r < 16; ++r) {
      int m = (r & 3) + 8 * (r >> 2) + 4 * half;  // pixel row in tile
      sc[m * 33 + m32] = acc[i][r];               // [pix][o]
    }
    size_t obase =
        ((((size_t)b * 32) * 6 + e1) * 6 + e2) * 3844 + (size_t)e3 * 62;
#pragma unroll
    for (int it = 0; it < 16; ++it) {
      int o = it * 2 + half;
      float v = fmaxf(sc[m32 * 33 + o], 0.f);
      if (e4 < 62) out[obase + (size_t)o * 138384 + e4] = v;
    }
  }
  __syncthreads();  // scratch reads done before a following unit restages
}

__device__ __forceinline__ void conv_unit(int unit,
                                          const unsigned char* __restrict__ ws,
                                          float* __restrict__ out,
                                          unsigned char* lds) {
  const unsigned char* wTb = ws + WT_OFF;
  const unsigned char* xbb = ws + XB_OFF;
  int g = unit % 72;      // (b,e1,e2): fixed XCD per group (72 % 8 == 0)
  int chunk = unit / 72;  // e3 chunk: 10 chunks of 6 rows + 1 of 2
  int b = g / 36;
  int e1 = (g / 6) % 6;
  int e2 = g % 6;
  int r0 = chunk * 6;
  if (chunk < 10)
    conv_body<3>(wTb, xbb, out, lds, b, e1, e2, r0);
  else
    conv_body<1>(wTb, xbb, out, lds, b, e1, e2, r0);
}

__global__ __launch_bounds__(256, 3) void conv_mfma(
    const unsigned char* __restrict__ ws, float* __restrict__ out) {
  __shared__ __align__(16) unsigned char lds[2 * BUF];
  conv_unit(blockIdx.x, ws, out, lds);
}

// ---- fused cooperative kernel: prep (grid-stride) -> grid.sync -> conv
__global__ __launch_bounds__(256, 3) void fused(const float* __restrict__ x,
                                                const float* __restrict__ w,
                                                unsigned char* __restrict__ ws,
                                                float* __restrict__ out) {
  __shared__ __align__(16) unsigned char lds[2 * BUF];
  int bid = blockIdx.x;
  for (int vb = bid; vb < 2080; vb += 768) prep_unit(vb, x, w, ws);
  cooperative_groups::this_grid().sync();
  for (int unit = bid; unit < 792; unit += 768) conv_unit(unit, ws, out, lds);
}

extern "C" void kernel_launch(void* const* d_in, const int* in_sizes, int n_in,
                              void* d_out, int out_size, void* d_ws,
                              size_t ws_size, hipStream_t stream) {
  const float* x = (const float*)d_in[0];
  const float* w = (const float*)d_in[1];
  float* out = (float*)d_out;
  unsigned char* ws = (unsigned char*)d_ws;

  void* args[] = {(void*)&x, (void*)&w, (void*)&ws, (void*)&out};
  hipError_t e = hipLaunchCooperativeKernel((const void*)fused, dim3(768),
                                            dim3(256), args, 0, stream);
  if (e != hipSuccess) {
    // fallback: proven two-kernel path
    prep<<<dim3(2080), dim3(256), 0, stream>>>(x, w, ws);
    conv_mfma<<<dim3(792), dim3(256), 0, stream>>>(ws, out);
  }
}

// Round 4
// 112.123 us; speedup vs baseline: 2.1762x; 2.1762x over previous
//
#include <hip/hip_runtime.h>

// x: [B=2, C=16, D1=8, D2=8, D3=64, D4=64] fp32
// w: [O=32, I=16, 3,3,3,3] fp32
// out = relu(conv4d_valid(x, w)): [2, 32, 6, 6, 62, 62] fp32
//
// Per tap: D[32 e4-pix][32 o] += A[pix][16 c] * B[16 c][32 o]
// (v_mfma_f32_32x32x16_bf16, fp32 acc, 81 taps).
// Block = (b,e1,e2, 6 e3 rows, 64 e4), 256 threads = 4 waves (R1
// structure, 111.0 us; R2 2-wave variant and R3 cooperative fusion both
// regressed - fusion spilled to scratch, VGPR 84, +75 MB writes).
// This round, two additive fixes on R1:
//  (1) wT tap layout [c-half][o][c8]: B ds_read becomes lane-contiguous
//      (half*512 + m32*16) - removes the ~1M SQ_LDS_BANK_CONFLICT cycles
//      the old m32*32 stride caused.
//  (2) chunk = (bid/72 + 10) % 11: the 72 light 2-row blocks dispatch
//      FIRST, absorbing the 792-vs-768-resident straggler tail.
// A tile (16 KB) + wT slice (9 KB) staged via global_load_lds,
// double-buffered; LDS 50.5 KB -> 3 blocks/CU. g = bid%72 pins a
// (b,e1,e2) group to one XCD (72 % 8 == 0).

typedef __attribute__((ext_vector_type(8))) __bf16 bf16x8;
typedef __attribute__((ext_vector_type(16))) float f32x16;

#define CSTRIDE 262144  // x channel stride, elements

#define WT_OFF 0       // wT[t81][ch2][o32][c8] bf16 = 83 KB
#define XB_OFF 131072  // xb[b][d1][d2][d3][ch2][col64][c8] bf16 = 16.78 MB
#define BOFF 16640     // B region inside a buffer (after 16 KB A + 256 pad)
#define BUF 25856      // per-buffer: A 16.25 KB + B 9 KB

typedef __attribute__((address_space(1))) const unsigned int gu32;
typedef __attribute__((address_space(3))) unsigned int lu32;

__device__ __forceinline__ void async_cp16(const void* g, void* l) {
  __builtin_amdgcn_global_load_lds((gu32*)g, (lu32*)l, 16, 0, 0);
}

// ---- prep: blocks 0..2047 transform x -> xb; blocks 2048..2079 build wT
__global__ __launch_bounds__(256) void prep(const float* __restrict__ x,
                                            const float* __restrict__ w,
                                            unsigned char* __restrict__ ws) {
  int blk = blockIdx.x;
  if (blk < 2048) {
    __bf16* xb = (__bf16*)(ws + XB_OFF);
    int n = blk * 256 + threadIdx.x;  // (b,d1,d2,d3,col)
    int col = n & 63;
    int d3 = (n >> 6) & 63;
    int d2 = (n >> 12) & 7;
    int d1 = (n >> 15) & 7;
    int b = n >> 18;
    const float* gx =
        x + ((((size_t)(b * 16) * 8 + d1) * 8 + d2) * 64 + d3) * 64 + col;
    float v[16];
#pragma unroll
    for (int c = 0; c < 16; ++c) v[c] = gx[(size_t)c * CSTRIDE];
    __bf16* row = xb + ((((b * 8 + d1) * 8 + d2) * 64 + d3) * 1024);
#pragma unroll
    for (int ch = 0; ch < 2; ++ch) {
      bf16x8 o;
#pragma unroll
      for (int cc = 0; cc < 8; ++cc) o[cc] = (__bf16)v[ch * 8 + cc];
      *(bf16x8*)(row + ch * 512 + col * 8) = o;
    }
  } else {
    int o = blk - 2048;
    __bf16* wT = (__bf16*)(ws + WT_OFF);
#pragma unroll
    for (int base = 0; base < 1296; base += 256) {
      int idx = base + threadIdx.x;
      if (idx < 1296) {
        int c = idx / 81, t = idx % 81;
        // [t][c>>3][o][c&7]: conv's B read is lane-contiguous (no bank
        // conflicts): byte off = t*1024 + half*512 + o*16 + (c&7)*2
        wT[t * 512 + (c >> 3) * 256 + o * 8 + (c & 7)] =
            (__bf16)w[o * 1296 + idx];
      }
    }
  }
}

// NT = tiles per wave (3 normal chunks, 1 for the 2-row tail chunk)
template <int NT>
__device__ __forceinline__ void conv_body(
    const unsigned char* __restrict__ wTb, const unsigned char* __restrict__ xbb,
    float* __restrict__ out, unsigned char* lds, int b, int e1, int e2,
    int r0) {
  int lane = threadIdx.x & 63;
  int wave = threadIdx.x >> 6;
  int m32 = lane & 31;
  int half = lane >> 5;
  int rg = wave >> 1;  // row-group
  int th = wave & 1;   // e4 half
  int rowbase = rg * NT;
  const int nckA = (NT * 2 + 2) * 2;  // staged A 1KB chunks: (rows+2 halo)*2
  const int nck = nckA + 9;           // + 9 B chunks

  int ab_off = half * 1024 + (th * 32 + m32) * 16;
  int bb_off = half * 512 + m32 * 16;  // lane-contiguous (conflict-free)

  f32x16 acc[NT];
#pragma unroll
  for (int i = 0; i < NT; ++i)
#pragma unroll
    for (int r = 0; r < 16; ++r) acc[i][r] = 0.f;

  // prologue: stage phase 0 (A tile + wT slice) into buf 0
  {
    const unsigned char* gA =
        xbb + (size_t)(((b * 8 + e1) * 8 + e2) * 64 + r0) * 2048;
#pragma unroll
    for (int j = 0; j < 7; ++j) {
      int ck = j * 4 + wave;
      if (ck < nckA)
        async_cp16(gA + ck * 1024 + lane * 16, lds + ck * 1024);
      else if (ck < nck)
        async_cp16(wTb + (ck - nckA) * 1024 + lane * 16,
                   lds + BOFF + (ck - nckA) * 1024);
    }
  }

  for (int p = 0; p < 9; ++p) {  // phase = (k1,k2)
    __syncthreads();  // stage(p) visible; buf[(p+1)&1] free
    if (p < 8) {
      int np = p + 1;
      int nk1 = np / 3, nk2 = np - nk1 * 3;
      const unsigned char* gA =
          xbb + (size_t)(((b * 8 + e1 + nk1) * 8 + e2 + nk2) * 64 + r0) * 2048;
      const unsigned char* gB = wTb + np * 9216;
      unsigned char* dst = lds + (np & 1) * BUF;
#pragma unroll
      for (int j = 0; j < 7; ++j) {
        int ck = j * 4 + wave;
        if (ck < nckA)
          async_cp16(gA + ck * 1024 + lane * 16, dst + ck * 1024);
        else if (ck < nck)
          async_cp16(gB + (ck - nckA) * 1024 + lane * 16,
                     dst + BOFF + (ck - nckA) * 1024);
      }
    }
    // compute: A and B from LDS; 5 row-frags serve 9 MFMAs per k4
    const unsigned char* bufp = lds + (p & 1) * BUF;
    bf16x8 bfr[9];
#pragma unroll
    for (int t9 = 0; t9 < 9; ++t9)
      bfr[t9] = *(const bf16x8*)(bufp + BOFF + t9 * 1024 + bb_off);
    const unsigned char* abase = bufp + rowbase * 2048 + ab_off;
    __builtin_amdgcn_s_setprio(1);
#pragma unroll
    for (int k4 = 0; k4 < 3; ++k4) {
      bf16x8 arow[NT + 2];
#pragma unroll
      for (int j = 0; j < NT + 2; ++j)
        arow[j] = *(const bf16x8*)(abase + j * 2048 + k4 * 16);
#pragma unroll
      for (int k3 = 0; k3 < 3; ++k3) {
        bf16x8 bf = bfr[k3 * 3 + k4];
#pragma unroll
        for (int i = 0; i < NT; ++i)
          acc[i] = __builtin_amdgcn_mfma_f32_32x32x16_bf16(arow[i + k3], bf,
                                                           acc[i], 0, 0, 0);
      }
    }
    __builtin_amdgcn_s_setprio(0);
  }
  __syncthreads();  // all ds_reads done before scratch overwrite

  // epilogue: per-wave LDS transpose (stride 33) in buf0 space, ReLU, store
  float* sc = (float*)(void*)lds + wave * 1056;
  int e4 = th * 32 + m32;
#pragma unroll
  for (int i = 0; i < NT; ++i) {
    int e3 = r0 + rowbase + i;
#pragma unroll
    for (int r = 0; r < 16; ++r) {
      int m = (r & 3) + 8 * (r >> 2) + 4 * half;  // pixel row in tile
      sc[m * 33 + m32] = acc[i][r];               // [pix][o]
    }
    size_t obase =
        ((((size_t)b * 32) * 6 + e1) * 6 + e2) * 3844 + (size_t)e3 * 62;
#pragma unroll
    for (int it = 0; it < 16; ++it) {
      int o = it * 2 + half;
      float v = fmaxf(sc[m32 * 33 + o], 0.f);
      if (e4 < 62) out[obase + (size_t)o * 138384 + e4] = v;
    }
  }
}

__global__ __launch_bounds__(256, 3) void conv_mfma(
    const unsigned char* __restrict__ ws, float* __restrict__ out) {
  const unsigned char* wTb = ws + WT_OFF;
  const unsigned char* xbb = ws + XB_OFF;

  __shared__ __align__(16) unsigned char lds[2 * BUF];

  int bid = blockIdx.x;
  int g = bid % 72;  // (b,e1,e2): fixed XCD per group (72 % 8 == 0)
  // light 2-row chunk (10) first so the 792-vs-768 straggler tail is
  // absorbed by early-finishing light blocks, not a 4th full round
  int chunk = (bid / 72 + 10) % 11;
  int b = g / 36;
  int e1 = (g / 6) % 6;
  int e2 = g % 6;
  int r0 = chunk * 6;

  if (chunk < 10)
    conv_body<3>(wTb, xbb, out, lds, b, e1, e2, r0);
  else
    conv_body<1>(wTb, xbb, out, lds, b, e1, e2, r0);
}

extern "C" void kernel_launch(void* const* d_in, const int* in_sizes, int n_in,
                              void* d_out, int out_size, void* d_ws,
                              size_t ws_size, hipStream_t stream) {
  const float* x = (const float*)d_in[0];
  const float* w = (const float*)d_in[1];
  float* out = (float*)d_out;
  unsigned char* ws = (unsigned char*)d_ws;
  prep<<<dim3(2080), dim3(256), 0, stream>>>(x, w, ws);
  conv_mfma<<<dim3(792), dim3(256), 0, stream>>>(ws, out);
}